// Round 6
// baseline (8383.257 us; speedup 1.0000x reference)
//
#include <hip/hip_runtime.h>
#include <stdint.h>

// AttentionBasedRewiring: sim = (x@Wq+bq) @ (x@Wk+bk)^T, top-8 per row.
// out[0 .. N*8)     = top-8 scores (fp32, descending)
// out[N*8 .. 2*N*8) = top-8 indices, written as float values
//
// FROZEN (bit-exact vs golden, validated round 5): proj_kernel's fp32
// sequential-fmaf chain and rescore's fp32 sequential-fmaf chain + stable
// top-8 select. Candidate generation only needs to produce a superset of
// the true top-8 per row.
//
// Round 6 (performance): sim kernel restructured —
//   * double-buffered 128KB swizzled K-tile LDS, 1 block/CU, lb(256,1)
//   * per-lane REGISTER top-8 per owned row (no sim dump, no scan, no
//     ballot): 8 rows x 8 sorted slots per lane
//   * T14 async staging: global->reg loads issued before compute,
//     split+ds_write after; ONE barrier per tile
//   * end: exact 16-way sorted-list merge -> top-16 per row -> rescore NC=16
//
// ws: [0,33554432) q32 | [33554432,67108864) k32 | [67108864,+4194304) cand

#define N_NODES 65536
#define D_IN    512
#define H_DIM   128
#define TOPK    8
#define NC      16
#define CTILE   128
#define NT      (N_NODES / CTILE)
#define RTILE   128
#define WS_REQ  ((size_t)71303168)

typedef __attribute__((ext_vector_type(8))) short short8;
typedef __attribute__((ext_vector_type(4))) short short4_;
typedef __attribute__((ext_vector_type(4))) float float4_;

__device__ __forceinline__ unsigned short f2bf(float f) {
  unsigned int u = __float_as_uint(f);
  u = u + 0x7fffu + ((u >> 16) & 1u);          // RNE
  return (unsigned short)(u >> 16);
}
__device__ __forceinline__ float bf2f(unsigned short h) {
  return __uint_as_float(((unsigned int)h) << 16);
}

// sorted descending top-8 insert, fully static indices (regs only)
__device__ __forceinline__ void ins8(float v, int ci, float* tv, int* ti) {
  #pragma unroll
  for (int s = 7; s >= 1; --s) {
    const bool up   = v > tv[s - 1];
    const bool here = v > tv[s];
    tv[s] = up ? tv[s - 1] : (here ? v : tv[s]);
    ti[s] = up ? ti[s - 1] : (here ? ci : ti[s]);
  }
  if (v > tv[0]) { tv[0] = v; ti[0] = ci; }
}

// ---------------- P: fp32 projections (FROZEN arithmetic) ----------------
__global__ __launch_bounds__(256) void proj_kernel(
    const float* __restrict__ x,
    const float* __restrict__ Wq, const float* __restrict__ bq,
    const float* __restrict__ Wk, const float* __restrict__ bk,
    float* __restrict__ q32, float* __restrict__ k32)
{
  const int tid = threadIdx.x;
  const int rowbase = blockIdx.x * 32;
  const int c = tid;
  const float* Wcol = (c < 128) ? (Wq + c) : (Wk + (c - 128));
  const float bias  = (c < 128) ? bq[c] : bk[c - 128];
  const float* xrow = x + (size_t)rowbase * D_IN;

  float acc[32];
  #pragma unroll
  for (int r = 0; r < 32; ++r) acc[r] = 0.f;

  for (int kc = 0; kc < D_IN; kc += 16) {
    float wv[16];
    #pragma unroll
    for (int u = 0; u < 16; ++u) wv[u] = Wcol[(size_t)(kc + u) * H_DIM];
    #pragma unroll
    for (int r = 0; r < 32; ++r) {
      #pragma unroll
      for (int u = 0; u < 16; ++u)
        acc[r] = fmaf(xrow[(size_t)r * D_IN + kc + u], wv[u], acc[r]);
    }
  }

  float* O = (c < 128) ? q32 : k32;
  const int h = c & 127;
  #pragma unroll 4
  for (int r = 0; r < 32; ++r)
    O[(size_t)(rowbase + r) * H_DIM + h] = acc[r] + bias;
}

// ------------- B: dbuf MFMA sim + per-lane register top-8 ------------------
__global__ __launch_bounds__(256, 1) void sim_topk_kernel(
    const float* __restrict__ q32, const float* __restrict__ k32,
    int* __restrict__ cand)
{
  // two 64KB swizzled K-tile buffers; reused as the merge scratch at the end
  __shared__ __align__(16) char smem[131104];

  const int tid  = threadIdx.x;
  const int lane = tid & 63;
  const int w    = tid >> 6;        // wave 0..3, owns rows [w*32, w*32+32)
  const int rgrp = lane >> 4;       // 0..3
  const int c16  = lane & 15;
  const int rowbase = blockIdx.x * RTILE;

  // ---- A-frags: split fp32 q -> bf16 hi/lo in-register (one-time) ----
  short8 afr[2][8];
  #pragma unroll
  for (int m = 0; m < 2; ++m) {
    const float* qr = q32 + (size_t)(rowbase + w * 32 + m * 16 + c16) * H_DIM;
    #pragma unroll
    for (int jw = 0; jw < 4; ++jw) {
      const float4* q4 = (const float4*)(qr + jw * 32 + rgrp * 8);
      float vv[8];
      { float4 a = q4[0], b = q4[1];
        vv[0]=a.x; vv[1]=a.y; vv[2]=a.z; vv[3]=a.w;
        vv[4]=b.x; vv[5]=b.y; vv[6]=b.z; vv[7]=b.w; }
      short8 hi, lo;
      #pragma unroll
      for (int u = 0; u < 8; ++u) {
        const unsigned short h = f2bf(vv[u]);
        hi[u] = (short)h;
        lo[u] = (short)f2bf(vv[u] - bf2f(h));
      }
      afr[m][jw]     = hi;   // hi plane: k-slice jw
      afr[m][jw + 4] = lo;   // lo plane: k-slice jw
    }
  }

  // ---- swizzled per-lane read offsets (constant over f,t) ----
  int roff[8];
  #pragma unroll
  for (int kk = 0; kk < 8; ++kk)
    roff[kk] = (kk * 64 + rgrp * 16) ^ ((c16 & 7) << 4);

  // ---- staging constants: thread handles (row j*8+rsub, float4 chunk f4) ----
  const int f4   = tid & 31;
  const int rsub = tid >> 5;                       // 0..7
  const int wo   = (f4 * 8) ^ (rsub << 4);         // swizzled within-row byte

  // ---- per-lane top-8 for each of 8 owned rows (ri = m*4+r2) ----
  float tv[8][8]; int ti[8][8];
  #pragma unroll
  for (int ri = 0; ri < 8; ++ri)
    #pragma unroll
    for (int s = 0; s < 8; ++s) { tv[ri][s] = -3.4e38f; ti[ri][s] = s; }

  // ---- prologue: stage tile 0 into buf 0 ----
  {
    char* dst = smem;
    #pragma unroll
    for (int j = 0; j < 16; ++j) {
      const float4 kv = *(const float4*)(k32 + (size_t)(j * 8 + rsub) * H_DIM + f4 * 4);
      short4_ hi4, lo4;
      { const unsigned short h0=f2bf(kv.x), h1=f2bf(kv.y), h2=f2bf(kv.z), h3=f2bf(kv.w);
        hi4[0]=(short)h0; hi4[1]=(short)h1; hi4[2]=(short)h2; hi4[3]=(short)h3;
        lo4[0]=(short)f2bf(kv.x-bf2f(h0)); lo4[1]=(short)f2bf(kv.y-bf2f(h1));
        lo4[2]=(short)f2bf(kv.z-bf2f(h2)); lo4[3]=(short)f2bf(kv.w-bf2f(h3)); }
      char* p = dst + (size_t)(j * 8 + rsub) * 512 + wo;
      *(short4_*)p         = hi4;
      *(short4_*)(p + 256) = lo4;
    }
  }
  __syncthreads();

  // ---- main loop: one barrier per tile ----
  #pragma unroll 1
  for (int t = 0; t < NT; ++t) {
    const int cur = t & 1, nxt = cur ^ 1;
    const bool pf = (t + 1 < NT);

    // issue next tile's global loads early (latency hides under MFMA)
    float4 kv[16];
    if (pf) {
      #pragma unroll
      for (int j = 0; j < 16; ++j)
        kv[j] = *(const float4*)(k32 + (size_t)((t + 1) * CTILE + j * 8 + rsub) * H_DIM + f4 * 4);
    }

    // compute from buf[cur]: f-pairs, 4 independent MFMA chains
    const char* kbase = smem + cur * 65536;
    #pragma unroll
    for (int fp = 0; fp < 4; ++fp) {
      const int f0 = fp * 2;
      short8 bfr[2][8];
      #pragma unroll
      for (int ff = 0; ff < 2; ++ff) {
        const char* kb = kbase + (size_t)((f0 + ff) * 16 + c16) * 512;
        #pragma unroll
        for (int kk = 0; kk < 8; ++kk)
          bfr[ff][kk] = *(const short8*)(kb + roff[kk]);
      }
      float4_ acc[2][2];
      acc[0][0] = (float4_){0.f,0.f,0.f,0.f}; acc[0][1] = (float4_){0.f,0.f,0.f,0.f};
      acc[1][0] = (float4_){0.f,0.f,0.f,0.f}; acc[1][1] = (float4_){0.f,0.f,0.f,0.f};
      #pragma unroll
      for (int kk = 0; kk < 8; ++kk) {
        // diag terms (qh*kh / ql*kl)
        acc[0][0] = __builtin_amdgcn_mfma_f32_16x16x32_bf16(afr[0][kk], bfr[0][kk], acc[0][0], 0, 0, 0);
        acc[0][1] = __builtin_amdgcn_mfma_f32_16x16x32_bf16(afr[0][kk], bfr[1][kk], acc[0][1], 0, 0, 0);
        acc[1][0] = __builtin_amdgcn_mfma_f32_16x16x32_bf16(afr[1][kk], bfr[0][kk], acc[1][0], 0, 0, 0);
        acc[1][1] = __builtin_amdgcn_mfma_f32_16x16x32_bf16(afr[1][kk], bfr[1][kk], acc[1][1], 0, 0, 0);
        // cross terms (qh*kl / ql*kh), same k-slice via swapped plane
        acc[0][0] = __builtin_amdgcn_mfma_f32_16x16x32_bf16(afr[0][kk], bfr[0][(kk + 4) & 7], acc[0][0], 0, 0, 0);
        acc[0][1] = __builtin_amdgcn_mfma_f32_16x16x32_bf16(afr[0][kk], bfr[1][(kk + 4) & 7], acc[0][1], 0, 0, 0);
        acc[1][0] = __builtin_amdgcn_mfma_f32_16x16x32_bf16(afr[1][kk], bfr[0][(kk + 4) & 7], acc[1][0], 0, 0, 0);
        acc[1][1] = __builtin_amdgcn_mfma_f32_16x16x32_bf16(afr[1][kk], bfr[1][(kk + 4) & 7], acc[1][1], 0, 0, 0);
      }
      // top-8 update from registers (D layout m89: col=lane&15, row=(lane>>4)*4+r2)
      #pragma unroll
      for (int m = 0; m < 2; ++m)
        #pragma unroll
        for (int ff = 0; ff < 2; ++ff) {
          const int col = t * CTILE + (f0 + ff) * 16 + c16;
          #pragma unroll
          for (int r2 = 0; r2 < 4; ++r2) {
            const float v = acc[m][ff][r2];
            if (v > tv[m * 4 + r2][7]) ins8(v, col, tv[m * 4 + r2], ti[m * 4 + r2]);
          }
        }
    }

    // split + write staged tile into buf[nxt]
    if (pf) {
      char* dst = smem + nxt * 65536;
      #pragma unroll
      for (int j = 0; j < 16; ++j) {
        short4_ hi4, lo4;
        { const unsigned short h0=f2bf(kv[j].x), h1=f2bf(kv[j].y), h2=f2bf(kv[j].z), h3=f2bf(kv[j].w);
          hi4[0]=(short)h0; hi4[1]=(short)h1; hi4[2]=(short)h2; hi4[3]=(short)h3;
          lo4[0]=(short)f2bf(kv[j].x-bf2f(h0)); lo4[1]=(short)f2bf(kv[j].y-bf2f(h1));
          lo4[2]=(short)f2bf(kv[j].z-bf2f(h2)); lo4[3]=(short)f2bf(kv[j].w-bf2f(h3)); }
        char* p = dst + (size_t)(j * 8 + rsub) * 512 + wo;
        *(short4_*)p         = hi4;
        *(short4_*)(p + 256) = lo4;
      }
    }
    __syncthreads();   // buf[cur] reads done; buf[nxt] writes visible
  }

  // ---- end merge: exact top-16-of-128 per row ----
  uint2* pairs = (uint2*)smem;   // [128 rows][16 lanes][8 slots]
  #pragma unroll
  for (int ri = 0; ri < 8; ++ri) {
    const int row = w * 32 + (ri >> 2) * 16 + rgrp * 4 + (ri & 3);
    #pragma unroll
    for (int s = 0; s < 8; ++s)
      pairs[((size_t)row * 16 + c16) * 8 + s] =
          make_uint2(__float_as_uint(tv[ri][s]), (unsigned)ti[ri][s]);
  }
  __syncthreads();

  if (tid < 128) {
    const int row = tid;
    int curq[16];
    #pragma unroll
    for (int l = 0; l < 16; ++l) curq[l] = 0;
    for (int it = 0; it < NC; ++it) {
      float bv = -3.4e38f; int bl = 0, bidx = 0;
      #pragma unroll
      for (int l = 0; l < 16; ++l) {
        const int cq = curq[l] < 8 ? curq[l] : 7;
        const uint2 p = pairs[((size_t)row * 16 + l) * 8 + cq];
        const float v = (curq[l] < 8) ? __uint_as_float(p.x) : -3.39e38f;
        if (v > bv) { bv = v; bl = l; bidx = (int)p.y; }
      }
      cand[(size_t)(rowbase + row) * NC + it] = bidx;
      #pragma unroll
      for (int l = 0; l < 16; ++l) curq[l] += (l == bl) ? 1 : 0;
    }
  }
}

// ------ R: fp32 sequential-fma rescore (FROZEN) of 16 cands + top-8 --------
__global__ __launch_bounds__(256) void rescore16_kernel(
    const float* __restrict__ q32, const float* __restrict__ k32,
    const int* __restrict__ cand, float* __restrict__ out)
{
  __shared__ float sv[16][NC];
  __shared__ int   si[16][NC];

  const int tid = threadIdx.x;
  const int rl  = tid >> 4;            // row-in-block 0..15
  const int j   = tid & 15;            // candidate slot
  const int row = blockIdx.x * 16 + rl;

  const int ci = cand[(size_t)row * NC + j] & (N_NODES - 1);
  const float4* qp = (const float4*)(q32 + (size_t)row * H_DIM);
  const float4* kp = (const float4*)(k32 + (size_t)ci * H_DIM);

  // strict single-accumulator ascending-h fmaf chain (vector loads only —
  // arithmetic order identical to the validated scalar chain)
  float s = 0.f;
  #pragma unroll 8
  for (int h4 = 0; h4 < H_DIM / 4; ++h4) {
    const float4 a = qp[h4], b = kp[h4];
    s = fmaf(a.x, b.x, s); s = fmaf(a.y, b.y, s);
    s = fmaf(a.z, b.z, s); s = fmaf(a.w, b.w, s);
  }
  sv[rl][j] = s;
  si[rl][j] = ci;
  __syncthreads();

  if (j == 0) {
    float lv[NC]; int li[NC];
    #pragma unroll
    for (int u = 0; u < NC; ++u) { lv[u] = sv[rl][u]; li[u] = si[rl][u]; }
    #pragma unroll
    for (int o = 0; o < TOPK; ++o) {
      float bs = -3.4e38f; int bi = 0x7fffffff; int bj = 0;
      #pragma unroll
      for (int u = 0; u < NC; ++u) {
        const bool better = (lv[u] > bs) || (lv[u] == bs && li[u] < bi);
        if (better) { bs = lv[u]; bi = li[u]; bj = u; }
      }
      lv[bj] = -3.4e38f;
      out[(size_t)row * TOPK + o] = bs;
      out[(size_t)N_NODES * TOPK + (size_t)row * TOPK + o] = (float)bi;
    }
  }
}

// sentinel: signals "ws too small" with a distinctive absmax signature
__global__ void sentinel_kernel(float* __restrict__ out) {
  const int i = blockIdx.x * 256 + threadIdx.x;
  out[i] = 0.0f;
  out[(size_t)N_NODES * TOPK + i] = 7777.0f;
}

extern "C" void kernel_launch(void* const* d_in, const int* in_sizes, int n_in,
                              void* d_out, int out_size, void* d_ws, size_t ws_size,
                              hipStream_t stream) {
  const float* x  = (const float*)d_in[0];
  const float* Wq = (const float*)d_in[1];
  const float* bq = (const float*)d_in[2];
  const float* Wk = (const float*)d_in[3];
  const float* bk = (const float*)d_in[4];
  float* out = (float*)d_out;

  if (ws_size < WS_REQ) {
    sentinel_kernel<<<N_NODES * TOPK / 256, 256, 0, stream>>>(out);
    return;
  }

  float* q32 = (float*)d_ws;                                   // 33.5 MB
  float* k32 = q32 + (size_t)N_NODES * H_DIM;                  // 33.5 MB
  int* cand  = (int*)((char*)d_ws + (size_t)67108864);         // 4.2 MB

  proj_kernel<<<N_NODES / 32, 256, 0, stream>>>(x, Wq, bq, Wk, bk, q32, k32);
  sim_topk_kernel<<<N_NODES / RTILE, 256, 0, stream>>>(q32, k32, cand);
  rescore16_kernel<<<N_NODES / 16, 256, 0, stream>>>(q32, k32, cand, out);
}

// Round 7
// 3517.471 us; speedup vs baseline: 2.3833x; 2.3833x over previous
//
#include <hip/hip_runtime.h>
#include <stdint.h>

// AttentionBasedRewiring: sim = (x@Wq+bq) @ (x@Wk+bk)^T, top-8 per row.
// out[0 .. N*8)     = top-8 scores (fp32, descending)
// out[N*8 .. 2*N*8) = top-8 indices, written as float values
//
// FROZEN (bit-exact vs golden, r5): proj_kernel's fp32 sequential-fmaf
// chain and rescore16's fp32 sequential-fmaf chain + stable top-8 select.
// Candidate generation only needs a superset of the true top-8 per row.
//
// Round 7: single-plane bf16 candidate sim (error ~0.04 rms, max ~0.2 <<
// 2.5 rank-8->16 margin => top-16 superset safe).
//   * 32KB K-tile (128 cols x 128 k bf16), lb(256,2) -> 2 blk/CU
//   * both-sides XOR swizzle (row&7 ^ half<<2)<<4: conflict-free writes+reads
//   * packed (key16|col16) per-lane register top-8 x 8 rows (64 VGPR)
//   * T14: next tile's global loads issued before compute
//   * end: 4-pass LDS merge (16 lanes x top-8 -> exact top-16) -> NC=16
//   * Kbf (bf16 K) precomputed once if ws >= 88.1MB; else in-kernel split
//
// ws: q32 [0,33.5M) | k32 [33.5M,67.1M) | cand [67.1M,71.3M) | Kbf [71.3M,88.1M)

#define N_NODES 65536
#define D_IN    512
#define H_DIM   128
#define TOPK    8
#define NC      16
#define CTILE   128
#define NT      (N_NODES / CTILE)
#define RTILE   128
#define WS_BASE ((size_t)71303168)
#define WS_KBF  ((size_t)88080384)

typedef __attribute__((ext_vector_type(8))) short short8;
typedef __attribute__((ext_vector_type(4))) float float4_;

__device__ __forceinline__ unsigned short f2bf(float f) {
  unsigned int u = __float_as_uint(f);
  u = u + 0x7fffu + ((u >> 16) & 1u);          // RNE
  return (unsigned short)(u >> 16);
}
__device__ __forceinline__ float bf2f(unsigned short h) {
  return __uint_as_float(((unsigned int)h) << 16);
}

// descending sorted insert into packed top-8 (all indices static)
__device__ __forceinline__ void ins8p(unsigned p, unsigned* tp) {
  #pragma unroll
  for (int s = 7; s >= 1; --s) {
    const bool up   = p > tp[s - 1];
    const bool here = p > tp[s];
    tp[s] = up ? tp[s - 1] : (here ? p : tp[s]);
  }
  if (p > tp[0]) tp[0] = p;
}

// ---------------- P: fp32 projections (FROZEN arithmetic) ----------------
__global__ __launch_bounds__(256) void proj_kernel(
    const float* __restrict__ x,
    const float* __restrict__ Wq, const float* __restrict__ bq,
    const float* __restrict__ Wk, const float* __restrict__ bk,
    float* __restrict__ q32, float* __restrict__ k32)
{
  const int tid = threadIdx.x;
  const int rowbase = blockIdx.x * 32;
  const int c = tid;
  const float* Wcol = (c < 128) ? (Wq + c) : (Wk + (c - 128));
  const float bias  = (c < 128) ? bq[c] : bk[c - 128];
  const float* xrow = x + (size_t)rowbase * D_IN;

  float acc[32];
  #pragma unroll
  for (int r = 0; r < 32; ++r) acc[r] = 0.f;

  for (int kc = 0; kc < D_IN; kc += 16) {
    float wv[16];
    #pragma unroll
    for (int u = 0; u < 16; ++u) wv[u] = Wcol[(size_t)(kc + u) * H_DIM];
    #pragma unroll
    for (int r = 0; r < 32; ++r) {
      #pragma unroll
      for (int u = 0; u < 16; ++u)
        acc[r] = fmaf(xrow[(size_t)r * D_IN + kc + u], wv[u], acc[r]);
    }
  }

  float* O = (c < 128) ? q32 : k32;
  const int h = c & 127;
  #pragma unroll 4
  for (int r = 0; r < 32; ++r)
    O[(size_t)(rowbase + r) * H_DIM + h] = acc[r] + bias;
}

// ---------------- Kbf: one-time fp32 -> bf16 (precompute path) -------------
__global__ __launch_bounds__(256) void kbf_kernel(
    const float* __restrict__ k32, unsigned short* __restrict__ Kbf)
{
  const size_t base = ((size_t)blockIdx.x * 256 + threadIdx.x) * 8;
  const float4 a = *(const float4*)(k32 + base);
  const float4 b = *(const float4*)(k32 + base + 4);
  short8 o;
  o[0] = (short)f2bf(a.x); o[1] = (short)f2bf(a.y);
  o[2] = (short)f2bf(a.z); o[3] = (short)f2bf(a.w);
  o[4] = (short)f2bf(b.x); o[5] = (short)f2bf(b.y);
  o[6] = (short)f2bf(b.z); o[7] = (short)f2bf(b.w);
  *(short8*)(Kbf + base) = o;
}

// ------------- B: single-plane bf16 MFMA sim + packed register top-8 -------
template<bool PRECOMP>
__global__ __launch_bounds__(256, 2) void sim_topk_kernel(
    const float* __restrict__ q32, const float* __restrict__ k32,
    const unsigned short* __restrict__ Kbf, int* __restrict__ cand)
{
  __shared__ __align__(16) char smem[32768];   // K tile / merge scratch

  const int tid  = threadIdx.x;
  const int lane = tid & 63;
  const int w    = tid >> 6;        // wave 0..3, owns rows [w*32, w*32+32)
  const int rgrp = lane >> 4;       // 0..3
  const int c16  = lane & 15;
  const int rowbase = blockIdx.x * RTILE;

  // ---- A-frags: fp32 q -> bf16 in-register (one-time, hi plane only) ----
  short8 afr[2][4];
  #pragma unroll
  for (int m = 0; m < 2; ++m) {
    const float* qr = q32 + (size_t)(rowbase + w * 32 + m * 16 + c16) * H_DIM;
    #pragma unroll
    for (int kk = 0; kk < 4; ++kk) {
      const float4 a = *(const float4*)(qr + kk * 32 + rgrp * 8);
      const float4 b = *(const float4*)(qr + kk * 32 + rgrp * 8 + 4);
      short8 hi;
      hi[0] = (short)f2bf(a.x); hi[1] = (short)f2bf(a.y);
      hi[2] = (short)f2bf(a.z); hi[3] = (short)f2bf(a.w);
      hi[4] = (short)f2bf(b.x); hi[5] = (short)f2bf(b.y);
      hi[6] = (short)f2bf(b.z); hi[7] = (short)f2bf(b.w);
      afr[m][kk] = hi;
    }
  }

  // ---- packed per-lane top-8 for 8 owned rows (ri = m*4+r2) ----
  // packed = (fp32 bits of max(v,0) >> 16) << 16 | col.  All true top-16
  // scores are >> 0, so positive-float bit ordering == value ordering.
  unsigned tp[8][8];
  #pragma unroll
  for (int ri = 0; ri < 8; ++ri)
    #pragma unroll
    for (int s = 0; s < 8; ++s) tp[ri][s] = 0u;

  // ---- staging mapping: thread -> (tile row srow, 128B half shalf) ----
  const int srow  = tid >> 1;
  const int shalf = tid & 1;
  int woff[8];
  #pragma unroll
  for (int j = 0; j < 8; ++j)
    woff[j] = srow * 256 +
              ((shalf * 128 + j * 16) ^ ((((srow & 7) ^ (shalf << 2))) << 4));

  // ---- per-lane B-read offsets (thread-constant) ----
  int rxor[4];
  #pragma unroll
  for (int kk = 0; kk < 4; ++kk)
    rxor[kk] = (kk * 64 + rgrp * 16) ^ ((((c16 & 7) ^ ((kk >> 1) << 2))) << 4);

  short8 kreg[8];     // precompute path staging regs
  float4 freg[16];    // fallback path staging regs

  // LOAD(t): issue global reads for tile t
  auto LOAD = [&](int t) {
    if constexpr (PRECOMP) {
      const unsigned short* src =
          Kbf + (size_t)(t * CTILE + srow) * H_DIM + shalf * 64;
      #pragma unroll
      for (int j = 0; j < 8; ++j) kreg[j] = *(const short8*)(src + j * 8);
    } else {
      const float* src = k32 + (size_t)(t * CTILE + srow) * H_DIM + shalf * 64;
      #pragma unroll
      for (int j = 0; j < 8; ++j) {
        freg[2 * j]     = *(const float4*)(src + j * 8);
        freg[2 * j + 1] = *(const float4*)(src + j * 8 + 4);
      }
    }
  };
  // WRITE: stage regs -> swizzled LDS
  auto WRITE = [&]() {
    #pragma unroll
    for (int j = 0; j < 8; ++j) {
      short8 v;
      if constexpr (PRECOMP) {
        v = kreg[j];
      } else {
        const float4 a = freg[2 * j], b = freg[2 * j + 1];
        v[0] = (short)f2bf(a.x); v[1] = (short)f2bf(a.y);
        v[2] = (short)f2bf(a.z); v[3] = (short)f2bf(a.w);
        v[4] = (short)f2bf(b.x); v[5] = (short)f2bf(b.y);
        v[6] = (short)f2bf(b.z); v[7] = (short)f2bf(b.w);
      }
      *(short8*)(smem + woff[j]) = v;
    }
  };

  LOAD(0);
  WRITE();
  __syncthreads();

  #pragma unroll 1
  for (int t = 0; t < NT; ++t) {
    if (t + 1 < NT) LOAD(t + 1);          // T14: issue early, hide under MFMA

    #pragma unroll
    for (int f = 0; f < 8; ++f) {
      const int row = f * 16 + c16;       // tile-local K row = sim col
      short8 bfr[4];
      #pragma unroll
      for (int kk = 0; kk < 4; ++kk)
        bfr[kk] = *(const short8*)(smem + row * 256 + rxor[kk]);

      float4_ a0 = (float4_){0.f, 0.f, 0.f, 0.f};
      float4_ a1 = (float4_){0.f, 0.f, 0.f, 0.f};
      #pragma unroll
      for (int kk = 0; kk < 4; ++kk) {
        a0 = __builtin_amdgcn_mfma_f32_16x16x32_bf16(afr[0][kk], bfr[kk], a0, 0, 0, 0);
        a1 = __builtin_amdgcn_mfma_f32_16x16x32_bf16(afr[1][kk], bfr[kk], a1, 0, 0, 0);
      }

      // D layout (m89): col = lane&15, row = (lane>>4)*4 + r2
      const unsigned col = (unsigned)(t * CTILE + f * 16 + c16);
      #pragma unroll
      for (int r2 = 0; r2 < 4; ++r2) {
        const unsigned p0 =
            (__float_as_uint(fmaxf(a0[r2], 0.f)) & 0xFFFF0000u) | col;
        if (p0 > tp[r2][7]) ins8p(p0, tp[r2]);
        const unsigned p1 =
            (__float_as_uint(fmaxf(a1[r2], 0.f)) & 0xFFFF0000u) | col;
        if (p1 > tp[4 + r2][7]) ins8p(p1, tp[4 + r2]);
      }
    }
    __syncthreads();                      // all reads of tile t done
    if (t + 1 < NT) WRITE();
    __syncthreads();                      // tile t+1 visible
  }

  // ---- 4-pass merge: 16 lanes x sorted-8 -> exact top-16 per row ----
  unsigned* pairs = (unsigned*)smem;      // [32 rows][16 c16][8]
  for (int p = 0; p < 4; ++p) {
    if (w == p) {
      #pragma unroll
      for (int ri = 0; ri < 8; ++ri) {
        const int rl = (ri >> 2) * 16 + rgrp * 4 + (ri & 3);  // 0..31
        #pragma unroll
        for (int s = 0; s < 8; ++s)
          pairs[((size_t)rl * 16 + c16) * 8 + s] = tp[ri][s];
      }
    }
    __syncthreads();
    if (tid < 32) {
      const int row = rowbase + p * 32 + tid;
      int cur[16];
      #pragma unroll
      for (int l = 0; l < 16; ++l) cur[l] = 0;
      for (int it = 0; it < NC; ++it) {
        unsigned best = 0u; int bl = 0;
        #pragma unroll
        for (int l = 0; l < 16; ++l) {
          const int cq = cur[l] < 8 ? cur[l] : 7;
          const unsigned v =
              (cur[l] < 8) ? pairs[((size_t)tid * 16 + l) * 8 + cq] : 0u;
          if (v > best) { best = v; bl = l; }
        }
        cand[(size_t)row * NC + it] = (int)(best & 0xFFFFu);
        #pragma unroll
        for (int l = 0; l < 16; ++l) cur[l] += (l == bl) ? 1 : 0;
      }
    }
    __syncthreads();
  }
}

// ------ R: fp32 sequential-fma rescore (FROZEN) of 16 cands + top-8 --------
__global__ __launch_bounds__(256) void rescore16_kernel(
    const float* __restrict__ q32, const float* __restrict__ k32,
    const int* __restrict__ cand, float* __restrict__ out)
{
  __shared__ float sv[16][NC];
  __shared__ int   si[16][NC];

  const int tid = threadIdx.x;
  const int rl  = tid >> 4;            // row-in-block 0..15
  const int j   = tid & 15;            // candidate slot
  const int row = blockIdx.x * 16 + rl;

  const int ci = cand[(size_t)row * NC + j] & (N_NODES - 1);
  const float4* qp = (const float4*)(q32 + (size_t)row * H_DIM);
  const float4* kp = (const float4*)(k32 + (size_t)ci * H_DIM);

  // strict single-accumulator ascending-h fmaf chain
  float s = 0.f;
  #pragma unroll 8
  for (int h4 = 0; h4 < H_DIM / 4; ++h4) {
    const float4 a = qp[h4], b = kp[h4];
    s = fmaf(a.x, b.x, s); s = fmaf(a.y, b.y, s);
    s = fmaf(a.z, b.z, s); s = fmaf(a.w, b.w, s);
  }
  sv[rl][j] = s;
  si[rl][j] = ci;
  __syncthreads();

  if (j == 0) {
    float lv[NC]; int li[NC];
    #pragma unroll
    for (int u = 0; u < NC; ++u) { lv[u] = sv[rl][u]; li[u] = si[rl][u]; }
    #pragma unroll
    for (int o = 0; o < TOPK; ++o) {
      float bs = -3.4e38f; int bi = 0x7fffffff; int bj = 0;
      #pragma unroll
      for (int u = 0; u < NC; ++u) {
        const bool better = (lv[u] > bs) || (lv[u] == bs && li[u] < bi);
        if (better) { bs = lv[u]; bi = li[u]; bj = u; }
      }
      lv[bj] = -3.4e38f;
      out[(size_t)row * TOPK + o] = bs;
      out[(size_t)N_NODES * TOPK + (size_t)row * TOPK + o] = (float)bi;
    }
  }
}

// sentinel: signals "ws too small" with a distinctive absmax signature
__global__ void sentinel_kernel(float* __restrict__ out) {
  const int i = blockIdx.x * 256 + threadIdx.x;
  out[i] = 0.0f;
  out[(size_t)N_NODES * TOPK + i] = 7777.0f;
}

extern "C" void kernel_launch(void* const* d_in, const int* in_sizes, int n_in,
                              void* d_out, int out_size, void* d_ws, size_t ws_size,
                              hipStream_t stream) {
  const float* x  = (const float*)d_in[0];
  const float* Wq = (const float*)d_in[1];
  const float* bq = (const float*)d_in[2];
  const float* Wk = (const float*)d_in[3];
  const float* bk = (const float*)d_in[4];
  float* out = (float*)d_out;

  if (ws_size < WS_BASE) {
    sentinel_kernel<<<N_NODES * TOPK / 256, 256, 0, stream>>>(out);
    return;
  }

  float* q32 = (float*)d_ws;                                     // 33.5 MB
  float* k32 = q32 + (size_t)N_NODES * H_DIM;                    // 33.5 MB
  int* cand  = (int*)((char*)d_ws + (size_t)67108864);           // 4.2 MB
  unsigned short* Kbf =
      (unsigned short*)((char*)d_ws + (size_t)71303168);         // 16.8 MB

  const bool precomp = (ws_size >= WS_KBF);

  proj_kernel<<<N_NODES / 32, 256, 0, stream>>>(x, Wq, bq, Wk, bk, q32, k32);
  if (precomp) {
    kbf_kernel<<<(N_NODES * H_DIM / 8) / 256, 256, 0, stream>>>(k32, Kbf);
    sim_topk_kernel<true><<<N_NODES / RTILE, 256, 0, stream>>>(q32, k32, Kbf, cand);
  } else {
    sim_topk_kernel<false><<<N_NODES / RTILE, 256, 0, stream>>>(q32, k32, Kbf, cand);
  }
  rescore16_kernel<<<N_NODES / 16, 256, 0, stream>>>(q32, k32, cand, out);
}

// Round 8
// 3400.440 us; speedup vs baseline: 2.4653x; 1.0344x over previous
//
#include <hip/hip_runtime.h>
#include <stdint.h>

// AttentionBasedRewiring: sim = (x@Wq+bq) @ (x@Wk+bk)^T, top-8 per row.
// out[0 .. N*8)     = top-8 scores (fp32, descending)
// out[N*8 .. 2*N*8) = top-8 indices, written as float values
//
// FROZEN (bit-exact vs golden, r5): proj_kernel's fp32 sequential-fmaf
// chain and rescore16's fp32 sequential-fmaf chain + stable top-8 select.
//
// Round 8: fix rule-#20 scratch spill of top-k state (r7: VGPR=84 => tp[8][8]
// lived in scratch => VALUBusy 48%).
//   * INS8: fully-static macro insert (no runtime indexing, no ptr-passing)
//   * fp32 threshold filter: 1 max-tree + branch per f; pack only on insert
//   * double-buffered 64KB LDS -> ONE barrier per tile
//   * distinct kernel names reveal precomp-vs-fallback path in the profile
//
// ws: q32 [0,33.5M) | k32 [33.5M,67.1M) | cand [67.1M,71.3M) | Kbf [71.3M,88.1M)

#define N_NODES 65536
#define D_IN    512
#define H_DIM   128
#define TOPK    8
#define NC      16
#define CTILE   128
#define NT      (N_NODES / CTILE)
#define RTILE   128
#define WS_BASE ((size_t)71303168)
#define WS_KBF  ((size_t)88080384)

typedef __attribute__((ext_vector_type(8))) short short8;
typedef __attribute__((ext_vector_type(4))) float float4_;

__device__ __forceinline__ unsigned short f2bf(float f) {
  unsigned int u = __float_as_uint(f);
  u = u + 0x7fffu + ((u >> 16) & 1u);          // RNE
  return (unsigned short)(u >> 16);
}
__device__ __forceinline__ float bf2f(unsigned short h) {
  return __uint_as_float(((unsigned int)h) << 16);
}

// fully-static descending sorted insert into packed top-8 row T[8].
// Statement order s=7..1 reads pre-update T[s-1] (matches sorted-shift), then
// slot 0.  All indices compile-time => SROA keeps T in VGPRs (rule #20).
#define INS8(T, P) do {                                                        \
    const unsigned _p = (P);                                                   \
    { const bool u=_p>T[6], h=_p>T[7]; T[7]=u?T[6]:(h?_p:T[7]); }              \
    { const bool u=_p>T[5], h=_p>T[6]; T[6]=u?T[5]:(h?_p:T[6]); }              \
    { const bool u=_p>T[4], h=_p>T[5]; T[5]=u?T[4]:(h?_p:T[5]); }              \
    { const bool u=_p>T[3], h=_p>T[4]; T[4]=u?T[3]:(h?_p:T[4]); }              \
    { const bool u=_p>T[2], h=_p>T[3]; T[3]=u?T[2]:(h?_p:T[3]); }              \
    { const bool u=_p>T[1], h=_p>T[2]; T[2]=u?T[1]:(h?_p:T[2]); }              \
    { const bool u=_p>T[0], h=_p>T[1]; T[1]=u?T[0]:(h?_p:T[1]); }              \
    if (_p > T[0]) T[0] = _p;                                                  \
  } while (0)

// ---------------- P: fp32 projections (FROZEN arithmetic) ----------------
__global__ __launch_bounds__(256) void proj_kernel(
    const float* __restrict__ x,
    const float* __restrict__ Wq, const float* __restrict__ bq,
    const float* __restrict__ Wk, const float* __restrict__ bk,
    float* __restrict__ q32, float* __restrict__ k32)
{
  const int tid = threadIdx.x;
  const int rowbase = blockIdx.x * 32;
  const int c = tid;
  const float* Wcol = (c < 128) ? (Wq + c) : (Wk + (c - 128));
  const float bias  = (c < 128) ? bq[c] : bk[c - 128];
  const float* xrow = x + (size_t)rowbase * D_IN;

  float acc[32];
  #pragma unroll
  for (int r = 0; r < 32; ++r) acc[r] = 0.f;

  for (int kc = 0; kc < D_IN; kc += 16) {
    float wv[16];
    #pragma unroll
    for (int u = 0; u < 16; ++u) wv[u] = Wcol[(size_t)(kc + u) * H_DIM];
    #pragma unroll
    for (int r = 0; r < 32; ++r) {
      #pragma unroll
      for (int u = 0; u < 16; ++u)
        acc[r] = fmaf(xrow[(size_t)r * D_IN + kc + u], wv[u], acc[r]);
    }
  }

  float* O = (c < 128) ? q32 : k32;
  const int h = c & 127;
  #pragma unroll 4
  for (int r = 0; r < 32; ++r)
    O[(size_t)(rowbase + r) * H_DIM + h] = acc[r] + bias;
}

// ---------------- Kbf: one-time fp32 -> bf16 (precompute path) -------------
__global__ __launch_bounds__(256) void kbf_kernel(
    const float* __restrict__ k32, unsigned short* __restrict__ Kbf)
{
  const size_t base = ((size_t)blockIdx.x * 256 + threadIdx.x) * 8;
  const float4 a = *(const float4*)(k32 + base);
  const float4 b = *(const float4*)(k32 + base + 4);
  short8 o;
  o[0] = (short)f2bf(a.x); o[1] = (short)f2bf(a.y);
  o[2] = (short)f2bf(a.z); o[3] = (short)f2bf(a.w);
  o[4] = (short)f2bf(b.x); o[5] = (short)f2bf(b.y);
  o[6] = (short)f2bf(b.z); o[7] = (short)f2bf(b.w);
  *(short8*)(Kbf + base) = o;
}

// ------------- B: single-plane bf16 MFMA sim + register top-8 --------------
template<bool PRECOMP>
__device__ __forceinline__ void sim_body(
    const float* __restrict__ q32, const float* __restrict__ k32,
    const unsigned short* __restrict__ Kbf, int* __restrict__ cand,
    char* smem)
{
  const int tid  = threadIdx.x;
  const int lane = tid & 63;
  const int w    = tid >> 6;        // wave 0..3, owns rows [w*32, w*32+32)
  const int rgrp = lane >> 4;       // 0..3
  const int c16  = lane & 15;
  const int rowbase = blockIdx.x * RTILE;

  // ---- A-frags: fp32 q -> bf16 in-register (one-time) ----
  short8 afr[2][4];
  #pragma unroll
  for (int m = 0; m < 2; ++m) {
    const float* qr = q32 + (size_t)(rowbase + w * 32 + m * 16 + c16) * H_DIM;
    #pragma unroll
    for (int kk = 0; kk < 4; ++kk) {
      const float4 a = *(const float4*)(qr + kk * 32 + rgrp * 8);
      const float4 b = *(const float4*)(qr + kk * 32 + rgrp * 8 + 4);
      short8 hi;
      hi[0] = (short)f2bf(a.x); hi[1] = (short)f2bf(a.y);
      hi[2] = (short)f2bf(a.z); hi[3] = (short)f2bf(a.w);
      hi[4] = (short)f2bf(b.x); hi[5] = (short)f2bf(b.y);
      hi[6] = (short)f2bf(b.z); hi[7] = (short)f2bf(b.w);
      afr[m][kk] = hi;
    }
  }

  // packed top-8 per owned row: (fp32bits(v) & 0xFFFF0000) | col.
  // thr[] = fp32 rejection threshold (bf16-truncated 8th value; start 0 --
  // true top-16 scores are all >> 0 so positive-bit ordering == value order).
  unsigned tp[8][8];
  float thr[8];
  #pragma unroll
  for (int ri = 0; ri < 8; ++ri) {
    thr[ri] = 0.f;
    #pragma unroll
    for (int s = 0; s < 8; ++s) tp[ri][s] = 0u;
  }

  // ---- staging mapping: thread -> (tile row srow, 128B half shalf) ----
  const int srow  = tid >> 1;
  const int shalf = tid & 1;
  int woff[8];
  #pragma unroll
  for (int j = 0; j < 8; ++j)
    woff[j] = srow * 256 +
              ((shalf * 128 + j * 16) ^ ((((srow & 7) ^ (shalf << 2))) << 4));

  // ---- per-lane B-read offsets (thread-constant) ----
  int rxor[4];
  #pragma unroll
  for (int kk = 0; kk < 4; ++kk)
    rxor[kk] = (kk * 64 + rgrp * 16) ^ ((((c16 & 7) ^ ((kk >> 1) << 2))) << 4);

  short8 kreg[8];     // precompute path staging regs
  float4 freg[16];    // fallback path staging regs

  auto LOAD = [&](int t) {
    if constexpr (PRECOMP) {
      const unsigned short* src =
          Kbf + (size_t)(t * CTILE + srow) * H_DIM + shalf * 64;
      #pragma unroll
      for (int j = 0; j < 8; ++j) kreg[j] = *(const short8*)(src + j * 8);
    } else {
      const float* src = k32 + (size_t)(t * CTILE + srow) * H_DIM + shalf * 64;
      #pragma unroll
      for (int j = 0; j < 8; ++j) {
        freg[2 * j]     = *(const float4*)(src + j * 8);
        freg[2 * j + 1] = *(const float4*)(src + j * 8 + 4);
      }
    }
  };
  auto WRITE = [&](char* dst) {
    #pragma unroll
    for (int j = 0; j < 8; ++j) {
      short8 v;
      if constexpr (PRECOMP) {
        v = kreg[j];
      } else {
        const float4 a = freg[2 * j], b = freg[2 * j + 1];
        v[0] = (short)f2bf(a.x); v[1] = (short)f2bf(a.y);
        v[2] = (short)f2bf(a.z); v[3] = (short)f2bf(a.w);
        v[4] = (short)f2bf(b.x); v[5] = (short)f2bf(b.y);
        v[6] = (short)f2bf(b.z); v[7] = (short)f2bf(b.w);
      }
      *(short8*)(dst + woff[j]) = v;
    }
  };

  LOAD(0);
  WRITE(smem);
  __syncthreads();

  #pragma unroll 1
  for (int t = 0; t < NT; ++t) {
    if (t + 1 < NT) LOAD(t + 1);          // issue early; hides under MFMA
    const char* kbase = smem + (t & 1) * 32768;

    #pragma unroll
    for (int f = 0; f < 8; ++f) {
      const int row = f * 16 + c16;       // tile-local K row = sim col
      short8 bfr[4];
      #pragma unroll
      for (int kk = 0; kk < 4; ++kk)
        bfr[kk] = *(const short8*)(kbase + row * 256 + rxor[kk]);

      float4_ a0 = (float4_){0.f, 0.f, 0.f, 0.f};
      float4_ a1 = (float4_){0.f, 0.f, 0.f, 0.f};
      #pragma unroll
      for (int kk = 0; kk < 4; ++kk) {
        a0 = __builtin_amdgcn_mfma_f32_16x16x32_bf16(afr[0][kk], bfr[kk], a0, 0, 0, 0);
        a1 = __builtin_amdgcn_mfma_f32_16x16x32_bf16(afr[1][kk], bfr[kk], a1, 0, 0, 0);
      }

      // cheap rejection: one max-tree vs thresholds, branch rarely taken
      const float d = fmaxf(
          fmaxf(fmaxf(a0[0] - thr[0], a0[1] - thr[1]),
                fmaxf(a0[2] - thr[2], a0[3] - thr[3])),
          fmaxf(fmaxf(a1[0] - thr[4], a1[1] - thr[5]),
                fmaxf(a1[2] - thr[6], a1[3] - thr[7])));

      if (__builtin_expect(d > 0.f, 0)) {
        const unsigned col = (unsigned)(t * CTILE + f * 16 + c16);
        #pragma unroll
        for (int r2 = 0; r2 < 4; ++r2) {
          if (a0[r2] > thr[r2]) {
            const unsigned p = (__float_as_uint(a0[r2]) & 0xFFFF0000u) | col;
            INS8(tp[r2], p);
            thr[r2] = __uint_as_float(tp[r2][7] & 0xFFFF0000u);
          }
          if (a1[r2] > thr[4 + r2]) {
            const unsigned p = (__float_as_uint(a1[r2]) & 0xFFFF0000u) | col;
            INS8(tp[4 + r2], p);
            thr[4 + r2] = __uint_as_float(tp[4 + r2][7] & 0xFFFF0000u);
          }
        }
      }
    }

    if (t + 1 < NT) WRITE(smem + ((t + 1) & 1) * 32768);
    __syncthreads();   // nxt staged for all; cur reads done before its reuse
  }

  // ---- 4-pass merge: 16 lanes x sorted-8 -> exact top-16 per row ----
  unsigned* pairs = (unsigned*)smem;      // [32 rows][16 c16][8] = 16 KB
  for (int p = 0; p < 4; ++p) {
    if (w == p) {
      #pragma unroll
      for (int ri = 0; ri < 8; ++ri) {
        const int rl = (ri >> 2) * 16 + rgrp * 4 + (ri & 3);  // 0..31
        #pragma unroll
        for (int s = 0; s < 8; ++s)
          pairs[((size_t)rl * 16 + c16) * 8 + s] = tp[ri][s];
      }
    }
    __syncthreads();
    if (tid < 32) {
      const int row = rowbase + p * 32 + tid;
      int cur[16];
      #pragma unroll
      for (int l = 0; l < 16; ++l) cur[l] = 0;
      for (int it = 0; it < NC; ++it) {
        unsigned best = 0u; int bl = 0;
        #pragma unroll
        for (int l = 0; l < 16; ++l) {
          const int cq = cur[l] < 8 ? cur[l] : 7;
          const unsigned v =
              (cur[l] < 8) ? pairs[((size_t)tid * 16 + l) * 8 + cq] : 0u;
          if (v > best) { best = v; bl = l; }
        }
        cand[(size_t)row * NC + it] = (int)(best & 0xFFFFu);
        #pragma unroll
        for (int l = 0; l < 16; ++l) cur[l] += (l == bl) ? 1 : 0;
      }
    }
    __syncthreads();
  }
}

__global__ __launch_bounds__(256, 2) void sim_topk_pre_kernel(
    const float* __restrict__ q32, const float* __restrict__ k32,
    const unsigned short* __restrict__ Kbf, int* __restrict__ cand)
{
  __shared__ __align__(16) char smem[65536];
  sim_body<true>(q32, k32, Kbf, cand, smem);
}

__global__ __launch_bounds__(256, 2) void sim_topk_fb_kernel(
    const float* __restrict__ q32, const float* __restrict__ k32,
    const unsigned short* __restrict__ Kbf, int* __restrict__ cand)
{
  __shared__ __align__(16) char smem[65536];
  sim_body<false>(q32, k32, Kbf, cand, smem);
}

// ------ R: fp32 sequential-fma rescore (FROZEN) of 16 cands + top-8 --------
__global__ __launch_bounds__(256) void rescore16_kernel(
    const float* __restrict__ q32, const float* __restrict__ k32,
    const int* __restrict__ cand, float* __restrict__ out)
{
  __shared__ float sv[16][NC];
  __shared__ int   si[16][NC];

  const int tid = threadIdx.x;
  const int rl  = tid >> 4;            // row-in-block 0..15
  const int j   = tid & 15;            // candidate slot
  const int row = blockIdx.x * 16 + rl;

  const int ci = cand[(size_t)row * NC + j] & (N_NODES - 1);
  const float4* qp = (const float4*)(q32 + (size_t)row * H_DIM);
  const float4* kp = (const float4*)(k32 + (size_t)ci * H_DIM);

  // strict single-accumulator ascending-h fmaf chain
  float s = 0.f;
  #pragma unroll 8
  for (int h4 = 0; h4 < H_DIM / 4; ++h4) {
    const float4 a = qp[h4], b = kp[h4];
    s = fmaf(a.x, b.x, s); s = fmaf(a.y, b.y, s);
    s = fmaf(a.z, b.z, s); s = fmaf(a.w, b.w, s);
  }
  sv[rl][j] = s;
  si[rl][j] = ci;
  __syncthreads();

  if (j == 0) {
    float lv[NC]; int li[NC];
    #pragma unroll
    for (int u = 0; u < NC; ++u) { lv[u] = sv[rl][u]; li[u] = si[rl][u]; }
    #pragma unroll
    for (int o = 0; o < TOPK; ++o) {
      float bs = -3.4e38f; int bi = 0x7fffffff; int bj = 0;
      #pragma unroll
      for (int u = 0; u < NC; ++u) {
        const bool better = (lv[u] > bs) || (lv[u] == bs && li[u] < bi);
        if (better) { bs = lv[u]; bi = li[u]; bj = u; }
      }
      lv[bj] = -3.4e38f;
      out[(size_t)row * TOPK + o] = bs;
      out[(size_t)N_NODES * TOPK + (size_t)row * TOPK + o] = (float)bi;
    }
  }
}

// sentinel: signals "ws too small" with a distinctive absmax signature
__global__ void sentinel_kernel(float* __restrict__ out) {
  const int i = blockIdx.x * 256 + threadIdx.x;
  out[i] = 0.0f;
  out[(size_t)N_NODES * TOPK + i] = 7777.0f;
}

extern "C" void kernel_launch(void* const* d_in, const int* in_sizes, int n_in,
                              void* d_out, int out_size, void* d_ws, size_t ws_size,
                              hipStream_t stream) {
  const float* x  = (const float*)d_in[0];
  const float* Wq = (const float*)d_in[1];
  const float* bq = (const float*)d_in[2];
  const float* Wk = (const float*)d_in[3];
  const float* bk = (const float*)d_in[4];
  float* out = (float*)d_out;

  if (ws_size < WS_BASE) {
    sentinel_kernel<<<N_NODES * TOPK / 256, 256, 0, stream>>>(out);
    return;
  }

  float* q32 = (float*)d_ws;                                     // 33.5 MB
  float* k32 = q32 + (size_t)N_NODES * H_DIM;                    // 33.5 MB
  int* cand  = (int*)((char*)d_ws + (size_t)67108864);           // 4.2 MB
  unsigned short* Kbf =
      (unsigned short*)((char*)d_ws + (size_t)71303168);         // 16.8 MB

  proj_kernel<<<N_NODES / 32, 256, 0, stream>>>(x, Wq, bq, Wk, bk, q32, k32);
  if (ws_size >= WS_KBF) {
    kbf_kernel<<<(N_NODES * H_DIM / 8) / 256, 256, 0, stream>>>(k32, Kbf);
    sim_topk_pre_kernel<<<N_NODES / RTILE, 256, 0, stream>>>(q32, k32, Kbf, cand);
  } else {
    sim_topk_fb_kernel<<<N_NODES / RTILE, 256, 0, stream>>>(q32, k32, Kbf, cand);
  }
  rescore16_kernel<<<N_NODES / 16, 256, 0, stream>>>(q32, k32, cand, out);
}